// Round 17
// baseline (542.067 us; speedup 1.0000x reference)
//
#include <hip/hip_runtime.h>

#define N_NODES 50000
#define N_EDGES 800000
// D_S=64, D_R=16, D_E=64, D_X=16, D_P=64, NUM_CLASSES=10
// W_r: [144,64]; W_o: [144,64]; W_s: [64,10] (all row-major)
//
// Linear refactor: scores[n] = u0[n] + deg_n*u1[n] + sum_{e->n} w_e
//   w_e  = u_s[s_e] + R_a[e]@A_R          (computed in EDGE order, streamed)
//   u_s[n] = O[n]@A_S ; u0[n] = O[n]@A_O + X[n]@A_X + c1 ; u1[n] = O[n]@A_dO + c0
// with Wc = W_o@W_s [144,10], Wc2 = Wc[80:144],
//   A_O = Wc[0:64], A_X = Wc[64:80], A_S = W_r[0:64]@Wc2,
//   A_R = W_r[128:144]@Wc2, A_dO = W_r[64:128]@Wc2,
//   c0 = b_r@Wc2, c1 = b_o@W_s + b_s.
//
// r9: only per-edge atomic in count_rank (return value = rank).
// r10: node_u table loads from LDS, vectorized O/X.
// r12: more ILP does NOT help edge_w (store-bound, ILP-invariant).
// r13: 64-bin LDS reduce = parallelism disaster.
// r14: nt stores regressed (L2 RMW merge was helping). edge_w ~52 us floor.
// r16: DAG-pair fusion 7->5 dispatches: -9 us (~4.5 us per boundary).
// r17 (this): PERSISTENT MEGA-KERNEL. 1024 blocks x 256 thr co-resident
// (launch_bounds(256,4) caps VGPR<=128 -> >=4 blocks/CU; LDS 10.2KB).
// Hand-rolled device-scope grid barrier (threadfence wbL2/invL2 for
// cross-XCD visibility, G16) replaces 3 dispatch boundaries. Phase bodies
// identical to r16 roles; edge_w phase thread-strided (imbalance = 1 edge).
//
// A-table layout in ws: [226][16] f32 (cols 10..15 zeroed):
//   rows 0..63 A_O | 64..79 A_X | 80..143 A_S | 144..159 A_R |
//   160..223 A_dO | 224 c0 | 225 c1

// ---------------------------------------------------------------------------
// Workspace layout (bytes) — end = 26,019,328 < 26,414,400 (proven in r3)
// ---------------------------------------------------------------------------
#define WS_A       ((size_t)0)          // 14,464 B
#define WS_COUNT   ((size_t)16384)      // 50000 i32 = 200,000 B
#define WS_CURSOR  ((size_t)216384)     // 1 u32
#define WS_BAR     ((size_t)216448)     // 3 barrier counters, 64B apart
#define WS_OFF     ((size_t)217088)     // 50000 i32 = 200,000 B
#define WS_RANK    ((size_t)417792)     // 800000 i32 = 3,200,000 B
#define WS_US      ((size_t)3618816)    // 50000*12 f32 = 2,400,000 B
#define WS_U01     ((size_t)6019072)    // 50000*20 f32 = 4,000,000 B
#define WS_WSORT   ((size_t)10019328)   // 800000*5 u32 = 16,000,000 B

#define NBLK   1024
#define NTHR   256
#define GSZ    (NBLK * NTHR)            // 262144 threads
#define NB_PRE   10                     // precompute_A blocks in P1
#define NB_ALLOC 196                    // alloc blocks in P2
#define CH_REC 512                      // node_score LDS chunk (records)

__device__ __forceinline__ unsigned int f32_to_bf16_rne(float f) {
    unsigned int x = __float_as_uint(f);
    return (x + 0x7fffu + ((x >> 16) & 1u)) >> 16;
}

// Device-scope grid barrier. Co-residency guaranteed by launch_bounds +
// grid <= 4 blocks/CU * 256 CU. threadfence = wbL2/invL2 (cross-XCD, G16).
__device__ __forceinline__ void grid_sync(int* bar, int idx) {
    __syncthreads();
    if (threadIdx.x == 0) {
        __threadfence();                       // flush my XCD's dirty L2
        atomicAdd(bar + idx * 16, 1);          // device-scope arrival
        while (__hip_atomic_load(bar + idx * 16, __ATOMIC_RELAXED,
                                 __HIP_MEMORY_SCOPE_AGENT) < NBLK)
            __builtin_amdgcn_s_sleep(8);
        __threadfence();                       // invalidate stale local L2
    }
    __syncthreads();
}

__global__ __launch_bounds__(NTHR, 4) void mega_kernel(
    const float* __restrict__ O, const float* __restrict__ X,
    const float* __restrict__ R_a,
    const int* __restrict__ senders, const int* __restrict__ receivers,
    const float* __restrict__ W_r, const float* __restrict__ b_r,
    const float* __restrict__ W_o, const float* __restrict__ b_o,
    const float* __restrict__ W_s, const float* __restrict__ b_s,
    float* __restrict__ A, int* __restrict__ count,
    unsigned int* __restrict__ cursor, int* __restrict__ bar,
    int* __restrict__ off, int* __restrict__ rank,
    float* __restrict__ us, float* __restrict__ u01,
    unsigned int* __restrict__ wsort, float* __restrict__ out)
{
    __shared__ union {
        float wc2[640];
        float2 lA[226 * 5];
        unsigned int lw[CH_REC * 5];
    } sm;

    const int t = threadIdx.x;
    const int b = blockIdx.x;
    const int gtid = b * NTHR + t;

    // ======================= P1: precompute_A || count_rank ================
    if (b < NB_PRE) {
        for (int idx = t; idx < 640; idx += NTHR) {
            const int row = 80 + idx / 10, c = idx % 10;
            float acc = 0.f;
            for (int j = 0; j < 64; ++j)
                acc = fmaf(W_o[row * 64 + j], W_s[j * 10 + c], acc);
            sm.wc2[idx] = acc;
        }
        __syncthreads();

        for (int g = b * NTHR + t; g < 3616; g += NB_PRE * NTHR) {
            if (g < 1356) {
                const int row = g / 6, c = 10 + g % 6;
                A[row * 16 + c] = 0.f;
            } else if (g < 2156) {
                const int i = g - 1356, row = i / 10, c = i % 10;
                float acc = 0.f;
                for (int j = 0; j < 64; ++j)
                    acc = fmaf(W_o[row * 64 + j], W_s[j * 10 + c], acc);
                A[row * 16 + c] = acc;
            } else if (g < 3596) {
                const int i = g - 2156, k = i / 10, c = i % 10;
                const int wrow = (k < 64) ? k : (k < 80 ? 128 + (k - 64) : 64 + (k - 80));
                const int arow = (k < 64) ? 80 + k : (k < 80 ? 144 + (k - 64) : 160 + (k - 80));
                const float* src = W_r + (size_t)wrow * 64;
                float acc = 0.f;
                for (int m = 0; m < 64; ++m)
                    acc = fmaf(src[m], sm.wc2[m * 10 + c], acc);
                A[arow * 16 + c] = acc;
            } else if (g < 3606) {
                const int c = g - 3596;
                float acc = 0.f;
                for (int m = 0; m < 64; ++m)
                    acc = fmaf(b_r[m], sm.wc2[m * 10 + c], acc);
                A[224 * 16 + c] = acc;
            } else {
                const int c = g - 3606;
                float acc = b_s[c];
                for (int j = 0; j < 64; ++j)
                    acc = fmaf(b_o[j], W_s[j * 10 + c], acc);
                A[225 * 16 + c] = acc;
            }
        }
    } else {
        const int bt = (b - NB_PRE) * NTHR + t;
        if (bt < N_EDGES / 4) {
            const int4 r4 = reinterpret_cast<const int4*>(receivers)[bt];
            int4 k4;
            k4.x = atomicAdd(count + r4.x, 1);
            k4.y = atomicAdd(count + r4.y, 1);
            k4.z = atomicAdd(count + r4.z, 1);
            k4.w = atomicAdd(count + r4.w, 1);
            reinterpret_cast<int4*>(rank)[bt] = k4;
        }
    }

    grid_sync(bar, 0);

    // ======================= P2: alloc || node_u ===========================
    if (b < NB_ALLOC) {
        const int n = b * NTHR + t;
        const int lane = t & 63;
        const int c = (n < N_NODES) ? count[n] : 0;

        int pre = c;
#pragma unroll
        for (int d = 1; d < 64; d <<= 1) {
            const int v = __shfl_up(pre, d);
            if (lane >= d) pre += v;
        }
        const int total = __shfl(pre, 63);
        int base = 0;
        if (lane == 63) base = (int)atomicAdd(cursor, (unsigned int)total);
        base = __shfl(base, 63);

        if (n < N_NODES) off[n] = base + pre - c;  // exclusive prefix
    } else {
        for (int i = t; i < 226 * 5; i += NTHR) {
            const int row = i / 5, cp = i - row * 5;
            sm.lA[i] = *reinterpret_cast<const float2*>(A + (size_t)row * 16 + 2 * cp);
        }
        __syncthreads();

        for (int tid = (b - NB_ALLOC) * NTHR + t; tid < N_NODES * 5;
             tid += (NBLK - NB_ALLOC) * NTHR) {
            const int n = tid / 5;
            const int cp = tid - n * 5;

            float vs0 = 0.f, vs1 = 0.f, v00 = 0.f, v01 = 0.f, v10 = 0.f, v11 = 0.f;

            const float4* Ov = reinterpret_cast<const float4*>(O + (size_t)n * 64);
#pragma unroll
            for (int kc = 0; kc < 16; ++kc) {
                const float4 o4 = Ov[kc];
#pragma unroll
                for (int j = 0; j < 4; ++j) {
                    const float ov = (j == 0) ? o4.x : (j == 1) ? o4.y : (j == 2) ? o4.z : o4.w;
                    const int k = kc * 4 + j;
                    const float2 aO = sm.lA[k * 5 + cp];
                    const float2 aS = sm.lA[(80 + k) * 5 + cp];
                    const float2 aD = sm.lA[(160 + k) * 5 + cp];
                    v00 = fmaf(ov, aO.x, v00); v01 = fmaf(ov, aO.y, v01);
                    vs0 = fmaf(ov, aS.x, vs0); vs1 = fmaf(ov, aS.y, vs1);
                    v10 = fmaf(ov, aD.x, v10); v11 = fmaf(ov, aD.y, v11);
                }
            }
            const float4* Xv = reinterpret_cast<const float4*>(X + (size_t)n * 16);
#pragma unroll
            for (int kc = 0; kc < 4; ++kc) {
                const float4 x4 = Xv[kc];
#pragma unroll
                for (int j = 0; j < 4; ++j) {
                    const float xv = (j == 0) ? x4.x : (j == 1) ? x4.y : (j == 2) ? x4.z : x4.w;
                    const int k = 64 + kc * 4 + j;
                    const float2 aX = sm.lA[k * 5 + cp];
                    v00 = fmaf(xv, aX.x, v00); v01 = fmaf(xv, aX.y, v01);
                }
            }

            const float2 c0 = sm.lA[224 * 5 + cp];
            const float2 c1 = sm.lA[225 * 5 + cp];
            *reinterpret_cast<float2*>(us + (size_t)n * 12 + 2 * cp) = make_float2(vs0, vs1);
            *reinterpret_cast<float2*>(u01 + (size_t)n * 20 + 2 * cp) =
                make_float2(v00 + c1.x, v01 + c1.y);
            *reinterpret_cast<float2*>(u01 + (size_t)n * 20 + 10 + 2 * cp) =
                make_float2(v10 + c0.x, v11 + c0.y);
        }
    }

    grid_sync(bar, 1);

    // ======================= P3: edge_w (thread-strided) ===================
    for (int e = gtid; e < N_EDGES; e += GSZ) {
        const int s = senders[e];
        const int r = receivers[e];
        const int pos = off[r] + rank[e];   // plain loads — no atomic

        const float4* U = reinterpret_cast<const float4*>(us + (size_t)s * 12);
        const float4 ua = U[0];
        const float4 ub = U[1];
        const float4 uc = U[2];
        float a[10] = {ua.x, ua.y, ua.z, ua.w, ub.x, ub.y, ub.z, ub.w, uc.x, uc.y};

        const float4* Rv = reinterpret_cast<const float4*>(R_a + (size_t)e * 16);
#pragma unroll
        for (int kc = 0; kc < 4; ++kc) {
            const float4 b4 = Rv[kc];
            const float* A0 = A + (size_t)(144 + kc * 4) * 16;
#pragma unroll
            for (int c = 0; c < 10; ++c) a[c] = fmaf(b4.x, A0[c], a[c]);
#pragma unroll
            for (int c = 0; c < 10; ++c) a[c] = fmaf(b4.y, A0[16 + c], a[c]);
#pragma unroll
            for (int c = 0; c < 10; ++c) a[c] = fmaf(b4.z, A0[32 + c], a[c]);
#pragma unroll
            for (int c = 0; c < 10; ++c) a[c] = fmaf(b4.w, A0[48 + c], a[c]);
        }

        unsigned int* wp = wsort + (size_t)pos * 5;
        wp[0] = f32_to_bf16_rne(a[0]) | (f32_to_bf16_rne(a[1]) << 16);
        wp[1] = f32_to_bf16_rne(a[2]) | (f32_to_bf16_rne(a[3]) << 16);
        wp[2] = f32_to_bf16_rne(a[4]) | (f32_to_bf16_rne(a[5]) << 16);
        wp[3] = f32_to_bf16_rne(a[6]) | (f32_to_bf16_rne(a[7]) << 16);
        wp[4] = f32_to_bf16_rne(a[8]) | (f32_to_bf16_rne(a[9]) << 16);
    }

    grid_sync(bar, 2);

    // ======================= P4: node_score (vb-strided) ===================
    for (int vb = b; vb < N_NODES / 16; vb += NBLK) {
        const int n0 = vb * 16;
        const int g = t >> 4;
        const int lane = t & 15;
        const int n = n0 + g;

        const int beg16 = off[n0];
        const int end16 = off[n0 + 15] + count[n0 + 15];

        const int beg = off[n];
        const int cnt = count[n];
        const int dge = cnt;

        const int cc = (lane < 10) ? lane : 0;
        const int half = cc >> 1;
        const int sh = (cc & 1) * 16;

        float sc = u01[(size_t)n * 20 + cc] + (float)dge * u01[(size_t)n * 20 + 10 + cc];

        for (int c0 = beg16; c0 < end16; c0 += CH_REC) {
            const int nrec = min(CH_REC, end16 - c0);
            const int ndw = nrec * 5;
            __syncthreads();
            for (int i = t; i < ndw; i += NTHR)
                sm.lw[i] = wsort[(size_t)c0 * 5 + i];
            __syncthreads();

            const int j0 = max(beg, c0);
            const int j1 = min(beg + cnt, c0 + nrec);
            for (int j = j0; j < j1; ++j) {
                const unsigned int v = sm.lw[(j - c0) * 5 + half];
                sc += __uint_as_float((v >> sh) << 16);
            }
        }

        float m = (lane < 10) ? sc : -3.0e38f;
#pragma unroll
        for (int d = 1; d < 16; d <<= 1) m = fmaxf(m, __shfl_xor(m, d, 16));
        const float ex = (lane < 10) ? __expf(sc - m) : 0.f;
        float sum = ex;
#pragma unroll
        for (int d = 1; d < 16; d <<= 1) sum += __shfl_xor(sum, d, 16);
        if (lane < 10) out[(size_t)n * 10 + lane] = ex / sum;
    }
}

extern "C" void kernel_launch(void* const* d_in, const int* in_sizes, int n_in,
                              void* d_out, int out_size, void* d_ws, size_t ws_size,
                              hipStream_t stream)
{
    const float* O    = (const float*)d_in[0];
    const float* X    = (const float*)d_in[1];
    const float* R_a  = (const float*)d_in[2];
    const int* senders   = (const int*)d_in[3];
    const int* receivers = (const int*)d_in[4];
    const float* W_r  = (const float*)d_in[5];
    const float* b_r  = (const float*)d_in[6];
    const float* W_o  = (const float*)d_in[7];
    const float* b_o  = (const float*)d_in[8];
    const float* W_s  = (const float*)d_in[9];
    const float* b_s  = (const float*)d_in[10];
    float* out = (float*)d_out;
    char* ws = (char*)d_ws;

    float* A      = (float*)(ws + WS_A);
    int* count    = (int*)(ws + WS_COUNT);
    unsigned int* cursor = (unsigned int*)(ws + WS_CURSOR);
    int* bar      = (int*)(ws + WS_BAR);
    int* off      = (int*)(ws + WS_OFF);
    int* rank     = (int*)(ws + WS_RANK);
    float* us     = (float*)(ws + WS_US);
    float* u01    = (float*)(ws + WS_U01);
    unsigned int* wsort = (unsigned int*)(ws + WS_WSORT);

    // zero count + cursor + barrier counters (contiguous region) in one memset
    hipMemsetAsync(count, 0, (size_t)(WS_BAR + 192 - WS_COUNT), stream);

    mega_kernel<<<NBLK, NTHR, 0, stream>>>(
        O, X, R_a, senders, receivers, W_r, b_r, W_o, b_o, W_s, b_s,
        A, count, cursor, bar, off, rank, us, u01, wsort, out);
}

// Round 18
// 117.234 us; speedup vs baseline: 4.6238x; 4.6238x over previous
//
#include <hip/hip_runtime.h>

#define N_NODES 50000
#define N_EDGES 800000
// D_S=64, D_R=16, D_E=64, D_X=16, D_P=64, NUM_CLASSES=10
// W_r: [144,64]; W_o: [144,64]; W_s: [64,10] (all row-major)
//
// Linear refactor: scores[n] = u0[n] + deg_n*u1[n] + sum_{e->n} w_e
//   w_e  = u_s[s_e] + R_a[e]@A_R          (computed in EDGE order, streamed)
//   u_s[n] = O[n]@A_S ; u0[n] = O[n]@A_O + X[n]@A_X + c1 ; u1[n] = O[n]@A_dO + c0
// with Wc = W_o@W_s [144,10], Wc2 = Wc[80:144],
//   A_O = Wc[0:64], A_X = Wc[64:80], A_S = W_r[0:64]@Wc2,
//   A_R = W_r[128:144]@Wc2, A_dO = W_r[64:128]@Wc2,
//   c0 = b_r@Wc2, c1 = b_o@W_s + b_s.
//
// r9: only per-edge atomic in count_rank (return value = rank).
// r10: node_u table loads from LDS, vectorized O/X.
// r12: more ILP does NOT help edge_w (store-bound, ILP-invariant).
// r13: 64-bin LDS reduce = parallelism disaster.
// r14: nt stores regressed (L2 RMW merge was helping). edge_w ~52 us floor.
// r16: DAG-pair fusion 7->5 dispatches: -9 us (~4.5 us per boundary). BEST.
// r17: persistent mega-kernel REGRESSED 4.6x — device-scope threadfence =
//      full L2 wb/inv per barrier on 8 non-coherent XCD L2s; every phase
//      restarted cold (FETCH 292 MB). Software grid barriers cannot beat
//      pipelined dispatch-boundary coherence. REVERTED to r16.
//
// A-table layout in ws: [226][16] f32 (cols 10..15 zeroed):
//   rows 0..63 A_O | 64..79 A_X | 80..143 A_S | 144..159 A_R |
//   160..223 A_dO | 224 c0 | 225 c1

// ---------------------------------------------------------------------------
// Workspace layout (bytes) — end = 26,019,328 < 26,414,400 (proven in r3)
// ---------------------------------------------------------------------------
#define WS_A       ((size_t)0)          // 14,464 B
#define WS_COUNT   ((size_t)16384)      // 50000 i32 = 200,000 B
#define WS_CURSOR  ((size_t)216384)     // 1 u32 (zeroed with count memset)
#define WS_OFF     ((size_t)217088)     // 50000 i32 = 200,000 B
#define WS_RANK    ((size_t)417792)     // 800000 i32 = 3,200,000 B
#define WS_US      ((size_t)3618816)    // 50000*12 f32 = 2,400,000 B
#define WS_U01     ((size_t)6019072)    // 50000*20 f32 = 4,000,000 B
#define WS_WSORT   ((size_t)10019328)   // 800000*5 u32 = 16,000,000 B

#define NB_PRE   10                     // precompute_A blocks
#define NB_CR    ((N_EDGES / 4 + 255) / 256)        // 782 count_rank blocks
#define NB_ALLOC ((N_NODES + 255) / 256)            // 196 alloc blocks
#define NB_NU    ((N_NODES * 5 + 255) / 256)        // 977 node_u blocks

__device__ __forceinline__ unsigned int f32_to_bf16_rne(float f) {
    unsigned int x = __float_as_uint(f);
    return (x + 0x7fffu + ((x >> 16) & 1u)) >> 16;
}

// ---------------------------------------------------------------------------
// Fused K1: blocks [0,NB_PRE) precompute A; blocks [NB_PRE,..) count+rank.
// Independent outputs (A vs count/rank) — safe to co-dispatch.
// ---------------------------------------------------------------------------
__global__ __launch_bounds__(256) void fused_prep_kernel(
    const float* __restrict__ W_r, const float* __restrict__ b_r,
    const float* __restrict__ W_o, const float* __restrict__ b_o,
    const float* __restrict__ W_s, const float* __restrict__ b_s,
    const int* __restrict__ receivers,
    float* __restrict__ A, int* __restrict__ count, int* __restrict__ rank)
{
    __shared__ float Wc2[640];  // used by precompute role only
    const int t = threadIdx.x;

    if (blockIdx.x < NB_PRE) {
        // ---- precompute_A role (grid-stride over NB_PRE blocks) ----
        for (int idx = t; idx < 640; idx += 256) {
            const int row = 80 + idx / 10, c = idx % 10;
            float acc = 0.f;
            for (int j = 0; j < 64; ++j)
                acc = fmaf(W_o[row * 64 + j], W_s[j * 10 + c], acc);
            Wc2[idx] = acc;
        }
        __syncthreads();

        for (int g = blockIdx.x * 256 + t; g < 3616; g += NB_PRE * 256) {
            if (g < 1356) {
                const int row = g / 6, c = 10 + g % 6;
                A[row * 16 + c] = 0.f;
            } else if (g < 2156) {
                const int i = g - 1356, row = i / 10, c = i % 10;
                float acc = 0.f;
                for (int j = 0; j < 64; ++j)
                    acc = fmaf(W_o[row * 64 + j], W_s[j * 10 + c], acc);
                A[row * 16 + c] = acc;
            } else if (g < 3596) {
                const int i = g - 2156, k = i / 10, c = i % 10;
                const int wrow = (k < 64) ? k : (k < 80 ? 128 + (k - 64) : 64 + (k - 80));
                const int arow = (k < 64) ? 80 + k : (k < 80 ? 144 + (k - 64) : 160 + (k - 80));
                const float* src = W_r + (size_t)wrow * 64;
                float acc = 0.f;
                for (int m = 0; m < 64; ++m)
                    acc = fmaf(src[m], Wc2[m * 10 + c], acc);
                A[arow * 16 + c] = acc;
            } else if (g < 3606) {
                const int c = g - 3596;
                float acc = 0.f;
                for (int m = 0; m < 64; ++m)
                    acc = fmaf(b_r[m], Wc2[m * 10 + c], acc);
                A[224 * 16 + c] = acc;
            } else {
                const int c = g - 3606;
                float acc = b_s[c];
                for (int j = 0; j < 64; ++j)
                    acc = fmaf(b_o[j], W_s[j * 10 + c], acc);
                A[225 * 16 + c] = acc;
            }
        }
    } else {
        // ---- count_rank role: atomic's return value IS the rank ----
        const int bt = (blockIdx.x - NB_PRE) * 256 + t;
        if (bt * 4 >= N_EDGES) return;
        const int4 r4 = reinterpret_cast<const int4*>(receivers)[bt];
        int4 k4;
        k4.x = atomicAdd(count + r4.x, 1);
        k4.y = atomicAdd(count + r4.y, 1);
        k4.z = atomicAdd(count + r4.z, 1);
        k4.w = atomicAdd(count + r4.w, 1);
        reinterpret_cast<int4*>(rank)[bt] = k4;
    }
}

// ---------------------------------------------------------------------------
// Fused K2: blocks [0,NB_ALLOC) segment-alloc; blocks [NB_ALLOC,..) node_u.
// alloc needs count (K1); node_u needs A (K1). Disjoint outputs.
// ---------------------------------------------------------------------------
__global__ __launch_bounds__(256) void fused_mid_kernel(
    const float* __restrict__ O, const float* __restrict__ X,
    const float* __restrict__ A,
    const int* __restrict__ count, unsigned int* __restrict__ cursor,
    int* __restrict__ off,
    float* __restrict__ us, float* __restrict__ u01)
{
    __shared__ float2 lA[226 * 5];  // used by node_u role only
    const int t = threadIdx.x;

    if (blockIdx.x < NB_ALLOC) {
        // ---- alloc role: wave-aggregated prefix, 1 atomic per wave.
        // Prefix is node-ordered within each 64-node wave chunk -> any
        // 16-aligned node group owns a contiguous wsort range (node_score).
        const int n = blockIdx.x * 256 + t;
        const int lane = t & 63;
        const int c = (n < N_NODES) ? count[n] : 0;

        int pre = c;
#pragma unroll
        for (int d = 1; d < 64; d <<= 1) {
            const int v = __shfl_up(pre, d);
            if (lane >= d) pre += v;
        }
        const int total = __shfl(pre, 63);
        int base = 0;
        if (lane == 63) base = (int)atomicAdd(cursor, (unsigned int)total);
        base = __shfl(base, 63);

        if (n < N_NODES) off[n] = base + pre - c;  // exclusive prefix
    } else {
        // ---- node_u role: thread = (node, class-PAIR), A staged in LDS ----
        for (int i = t; i < 226 * 5; i += 256) {
            const int row = i / 5, cp = i - row * 5;
            lA[i] = *reinterpret_cast<const float2*>(A + (size_t)row * 16 + 2 * cp);
        }
        __syncthreads();

        const int tid = (blockIdx.x - NB_ALLOC) * 256 + t;
        if (tid >= N_NODES * 5) return;
        const int n = tid / 5;
        const int cp = tid - n * 5;

        float vs0 = 0.f, vs1 = 0.f, v00 = 0.f, v01 = 0.f, v10 = 0.f, v11 = 0.f;

        const float4* Ov = reinterpret_cast<const float4*>(O + (size_t)n * 64);
#pragma unroll
        for (int kc = 0; kc < 16; ++kc) {
            const float4 o4 = Ov[kc];
#pragma unroll
            for (int j = 0; j < 4; ++j) {
                const float ov = (j == 0) ? o4.x : (j == 1) ? o4.y : (j == 2) ? o4.z : o4.w;
                const int k = kc * 4 + j;
                const float2 aO = lA[k * 5 + cp];
                const float2 aS = lA[(80 + k) * 5 + cp];
                const float2 aD = lA[(160 + k) * 5 + cp];
                v00 = fmaf(ov, aO.x, v00); v01 = fmaf(ov, aO.y, v01);
                vs0 = fmaf(ov, aS.x, vs0); vs1 = fmaf(ov, aS.y, vs1);
                v10 = fmaf(ov, aD.x, v10); v11 = fmaf(ov, aD.y, v11);
            }
        }
        const float4* Xv = reinterpret_cast<const float4*>(X + (size_t)n * 16);
#pragma unroll
        for (int kc = 0; kc < 4; ++kc) {
            const float4 x4 = Xv[kc];
#pragma unroll
            for (int j = 0; j < 4; ++j) {
                const float xv = (j == 0) ? x4.x : (j == 1) ? x4.y : (j == 2) ? x4.z : x4.w;
                const int k = 64 + kc * 4 + j;
                const float2 aX = lA[k * 5 + cp];
                v00 = fmaf(xv, aX.x, v00); v01 = fmaf(xv, aX.y, v01);
            }
        }

        const float2 c0 = lA[224 * 5 + cp];
        const float2 c1 = lA[225 * 5 + cp];
        *reinterpret_cast<float2*>(us + (size_t)n * 12 + 2 * cp) = make_float2(vs0, vs1);
        *reinterpret_cast<float2*>(u01 + (size_t)n * 20 + 2 * cp) =
            make_float2(v00 + c1.x, v01 + c1.y);
        *reinterpret_cast<float2*>(u01 + (size_t)n * 20 + 10 + 2 * cp) =
            make_float2(v10 + c0.x, v11 + c0.y);
    }
}

// ---------------------------------------------------------------------------
// Per-edge w_e = u_s[s_e] + R_a[e]@A_R -> bf16-packed, written directly to
// receiver-sorted slot pos = off[r] + rank[e]. No atomic. Plain stores.
// ---------------------------------------------------------------------------
__global__ __launch_bounds__(256) void edge_w_kernel(
    const float* __restrict__ R_a,
    const int* __restrict__ senders, const int* __restrict__ receivers,
    const int* __restrict__ rank, const int* __restrict__ off,
    const float* __restrict__ us, const float* __restrict__ A,
    unsigned int* __restrict__ wsort)   // [E][5] dwords, receiver-sorted
{
    const int e = blockIdx.x * blockDim.x + threadIdx.x;
    if (e >= N_EDGES) return;
    const int s = senders[e];
    const int r = receivers[e];
    const int pos = off[r] + rank[e];   // plain loads — no atomic

    // u_s[s]: 48 B gather from L2-resident 2.4 MB table
    const float4* U = reinterpret_cast<const float4*>(us + (size_t)s * 12);
    const float4 ua = U[0];
    const float4 ub = U[1];
    const float4 uc = U[2];
    float a[10] = {ua.x, ua.y, ua.z, ua.w, ub.x, ub.y, ub.z, ub.w, uc.x, uc.y};

    // R_a[e] @ A_R (A rows 144..159) — R_a streamed coalesced
    const float4* Rv = reinterpret_cast<const float4*>(R_a + (size_t)e * 16);
#pragma unroll
    for (int kc = 0; kc < 4; ++kc) {
        const float4 b4 = Rv[kc];
        const float* A0 = A + (size_t)(144 + kc * 4) * 16;
#pragma unroll
        for (int c = 0; c < 10; ++c) a[c] = fmaf(b4.x, A0[c], a[c]);
#pragma unroll
        for (int c = 0; c < 10; ++c) a[c] = fmaf(b4.y, A0[16 + c], a[c]);
#pragma unroll
        for (int c = 0; c < 10; ++c) a[c] = fmaf(b4.z, A0[32 + c], a[c]);
#pragma unroll
        for (int c = 0; c < 10; ++c) a[c] = fmaf(b4.w, A0[48 + c], a[c]);
    }

    unsigned int* wp = wsort + (size_t)pos * 5;
    wp[0] = f32_to_bf16_rne(a[0]) | (f32_to_bf16_rne(a[1]) << 16);
    wp[1] = f32_to_bf16_rne(a[2]) | (f32_to_bf16_rne(a[3]) << 16);
    wp[2] = f32_to_bf16_rne(a[4]) | (f32_to_bf16_rne(a[5]) << 16);
    wp[3] = f32_to_bf16_rne(a[6]) | (f32_to_bf16_rne(a[7]) << 16);
    wp[4] = f32_to_bf16_rne(a[8]) | (f32_to_bf16_rne(a[9]) << 16);
}

// ---------------------------------------------------------------------------
// Node scores (r15): block = 16 aligned nodes = one CONTIGUOUS wsort range.
// Stream range into LDS coalesced (512-record chunks), reduce from LDS.
// ---------------------------------------------------------------------------
#define CH_REC 512   // records per LDS chunk (2560 dwords = 10,240 B)

__global__ __launch_bounds__(256) void node_score_kernel(
    const float* __restrict__ u01,
    const int* __restrict__ off, const int* __restrict__ count,
    const unsigned int* __restrict__ w,   // [E][5] dwords, receiver-sorted
    float* __restrict__ out)
{
    __shared__ unsigned int lw[CH_REC * 5];
    const int t = threadIdx.x;
    const int n0 = blockIdx.x * 16;        // 16 | 64 -> block range contiguous
    const int g = t >> 4;                  // group 0..15 -> node n0+g
    const int lane = t & 15;
    const int n = n0 + g;                  // N_NODES % 16 == 0

    const int beg16 = off[n0];
    const int end16 = off[n0 + 15] + count[n0 + 15];

    const int beg = off[n];
    const int cnt = count[n];
    const int dge = cnt;

    const int cc = (lane < 10) ? lane : 0;
    const int half = cc >> 1;
    const int sh = (cc & 1) * 16;

    float sc = u01[(size_t)n * 20 + cc] + (float)dge * u01[(size_t)n * 20 + 10 + cc];

    for (int c0 = beg16; c0 < end16; c0 += CH_REC) {
        const int nrec = min(CH_REC, end16 - c0);
        const int ndw = nrec * 5;
        __syncthreads();
        for (int i = t; i < ndw; i += 256)
            lw[i] = w[(size_t)c0 * 5 + i];
        __syncthreads();

        const int j0 = max(beg, c0);
        const int j1 = min(beg + cnt, c0 + nrec);
        for (int j = j0; j < j1; ++j) {
            const unsigned int v = lw[(j - c0) * 5 + half];
            sc += __uint_as_float((v >> sh) << 16);
        }
    }

    // softmax over the 10 active lanes of this 16-lane group
    float m = (lane < 10) ? sc : -3.0e38f;
#pragma unroll
    for (int d = 1; d < 16; d <<= 1) m = fmaxf(m, __shfl_xor(m, d, 16));
    const float ex = (lane < 10) ? __expf(sc - m) : 0.f;
    float sum = ex;
#pragma unroll
    for (int d = 1; d < 16; d <<= 1) sum += __shfl_xor(sum, d, 16);
    if (lane < 10) out[(size_t)n * 10 + lane] = ex / sum;
}

extern "C" void kernel_launch(void* const* d_in, const int* in_sizes, int n_in,
                              void* d_out, int out_size, void* d_ws, size_t ws_size,
                              hipStream_t stream)
{
    const float* O    = (const float*)d_in[0];
    const float* X    = (const float*)d_in[1];
    const float* R_a  = (const float*)d_in[2];
    const int* senders   = (const int*)d_in[3];
    const int* receivers = (const int*)d_in[4];
    const float* W_r  = (const float*)d_in[5];
    const float* b_r  = (const float*)d_in[6];
    const float* W_o  = (const float*)d_in[7];
    const float* b_o  = (const float*)d_in[8];
    const float* W_s  = (const float*)d_in[9];
    const float* b_s  = (const float*)d_in[10];
    float* out = (float*)d_out;
    char* ws = (char*)d_ws;

    float* A      = (float*)(ws + WS_A);
    int* count    = (int*)(ws + WS_COUNT);
    unsigned int* cursor = (unsigned int*)(ws + WS_CURSOR);
    int* off      = (int*)(ws + WS_OFF);
    int* rank     = (int*)(ws + WS_RANK);
    float* us     = (float*)(ws + WS_US);
    float* u01    = (float*)(ws + WS_U01);
    unsigned int* wsort = (unsigned int*)(ws + WS_WSORT);

    // zero count histogram + cursor (adjacent) in one memset
    hipMemsetAsync(count, 0, (size_t)(200000 + 4 + 384), stream);

    fused_prep_kernel<<<NB_PRE + NB_CR, 256, 0, stream>>>(
        W_r, b_r, W_o, b_o, W_s, b_s, receivers, A, count, rank);

    fused_mid_kernel<<<NB_ALLOC + NB_NU, 256, 0, stream>>>(
        O, X, A, count, cursor, off, us, u01);

    edge_w_kernel<<<(N_EDGES + 255) / 256, 256, 0, stream>>>(
        R_a, senders, receivers, rank, off, us, A, wsort);

    node_score_kernel<<<N_NODES / 16, 256, 0, stream>>>(
        u01, off, count, wsort, out);
}